// Round 6
// baseline (7725.981 us; speedup 1.0000x reference)
//
#include <hip/hip_runtime.h>
#include <cmath>

#define TSTEPS 256
#define DIM 1024
#define GST 35            // gate scratch col-stride (32+3): <=3-way LDS conflicts

typedef _Float16 half8v __attribute__((ext_vector_type(8)));
typedef _Float16 half4v __attribute__((ext_vector_type(4)));
typedef float f32x4 __attribute__((ext_vector_type(4)));

// ws layout (halfs):
//   xh  : [B][T][D] fp16 x, 16,777,216 halfs
//   h0r : [4 slot][64][1024] ring for h0, 262,144 halfs
//   h1r : [4 slot][64][1024] ring for h1, 262,144 halfs
//   cnt0/cnt1 : per-phase completion counters (256 each)
// Phase p: cell0 computes h0[t=p] (reads x[p], h0[p-1]); cell1 computes
// h1[t=p-1] (reads h0[p-1], h1[p-2]). h[t] lives in ring slot t&3.

__global__ void prologue(const float* __restrict__ x, _Float16* __restrict__ xh,
                         _Float16* __restrict__ hrings, unsigned* __restrict__ cnts)
{
    size_t gid  = (size_t)blockIdx.x * blockDim.x + threadIdx.x;
    size_t nthr = (size_t)gridDim.x * blockDim.x;
    for (size_t i = gid; i < 4194304u; i += nthr) {
        float4 v = ((const float4*)x)[i];
        half4v h = {(_Float16)v.x, (_Float16)v.y, (_Float16)v.z, (_Float16)v.w};
        ((half4v*)xh)[i] = h;
    }
    for (size_t i = gid; i < 65536u; i += nthr) {   // zero both h rings
        half8v z = {};
        ((half8v*)hrings)[i] = z;
    }
    if (gid < 512) cnts[gid] = 0u;
}

__device__ __forceinline__ void poll_ge(const unsigned* c, unsigned tgt) {
    while (__hip_atomic_load(c, __ATOMIC_RELAXED, __HIP_MEMORY_SCOPE_AGENT) < tgt)
        __builtin_amdgcn_s_sleep(4);
}

// 256 blocks x 512 threads. Blocks 0..127: cell0; 128..255: cell1. Block owns
// 32 gate-cols = 8 h-dims. Wave kq owns K-slice [kq*256, kq*256+256), weights
// in registers (16 x half8v). h reads are plain cached loads (L2-amplified);
// coherence via per-phase agent acquire fence (L1/L2 inv) AFTER the poll
// succeeds. h writes are agent-scope write-through (no dirty L2 lines).
// Sync: per-phase counters, one poller/block with s_sleep backoff (no spin
// storm), decoupled deps so cell0 can run ~2 phases ahead of cell1.
__global__ __launch_bounds__(512, 1)
void lstm_persistent(const float* __restrict__ Wx0, const float* __restrict__ Wh0,
                     const float* __restrict__ b0,
                     const float* __restrict__ Wx1, const float* __restrict__ Wh1,
                     const float* __restrict__ b1,
                     const _Float16* __restrict__ xh, _Float16* __restrict__ h0r,
                     _Float16* __restrict__ h1r, unsigned* __restrict__ cnt0,
                     unsigned* __restrict__ cnt1, float* __restrict__ out)
{
    extern __shared__ char smem[];
    _Float16* wfrag = (_Float16*)smem;          // 128 KB staging (dead after init)
    float*    gates = (float*)smem;             // [8 kq][64 m][GST] fp32, aliases

    const int tid  = threadIdx.x;
    const int blk  = blockIdx.x;
    const int cell = blk >> 7;
    const int wb   = blk & 127;
    const int lane = tid & 63, kq = tid >> 6;
    const int n15 = lane & 15, q = lane >> 4;

    // ---- one-time: weights -> LDS in B-fragment order (fp32->fp16) ----
    const float* m0 = cell ? Wx1 : Wx0;
    const float* m1 = cell ? Wh1 : Wh0;
    for (int idx = tid; idx < 16384; idx += 512) {
        int k = idx >> 3;
        int cc0 = (idx & 7) * 4;
        int g = cc0 >> 3, c = cc0 & 7;
        const float* src = (k < 1024 ? m0 + (size_t)k * 4096
                                     : m1 + (size_t)(k - 1024) * 4096)
                           + g * 1024 + wb * 8 + c;
        float4 v = *(const float4*)src;
        int skq = k >> 8, kt = (k >> 5) & 7, sq = (k >> 3) & 3, j = k & 7;
        float vv[4] = {v.x, v.y, v.z, v.w};
        #pragma unroll
        for (int e = 0; e < 4; ++e) {
            int cc = cc0 + e, nt = cc >> 4, nn = cc & 15;
            wfrag[((((skq * 2 + nt) * 8 + kt) * 64) + sq * 16 + nn) * 8 + j] = (_Float16)vv[e];
        }
    }
    __syncthreads();

    half8v wreg[16];                      // [nt*8 + kt]
    #pragma unroll
    for (int nt = 0; nt < 2; ++nt)
        #pragma unroll
        for (int kt = 0; kt < 8; ++kt)
            wreg[nt * 8 + kt] = *(const half8v*)
                &wfrag[((((kq * 2 + nt) * 8 + kt) * 64) + lane) * 8];
    __syncthreads();                      // wfrag dead; gates alias it

    const int pb = tid >> 3, pd = tid & 7;
    const float* bias = cell ? b1 : b0;
    const int gdim = wb * 8 + pd;
    const float bi = bias[0 * 1024 + gdim], bfg = bias[1 * 1024 + gdim],
                bg = bias[2 * 1024 + gdim], bo  = bias[3 * 1024 + gdim];
    float creg = 0.0f;

    for (int p = 0; p <= TSTEPS; ++p) {
        if (cell == 0 && p == TSTEPS) break;   // cell0 done after phase 255

        // ---- wait for dependencies (one poller, sleep backoff) ----
        if (p >= 1) {
            if (tid == 0) {
                poll_ge(cnt0 + (p - 1), 128u);               // h0[p-1] ready
                if (cell == 0) {
                    if (p >= 3) poll_ge(cnt1 + (p - 3), 128u);  // WAR: h0 ring
                } else {
                    if (p >= 2) poll_ge(cnt1 + (p - 1), 128u);  // h1[p-2] ready
                }
            }
            __syncthreads();
            // make other XCDs' h stores visible to our cached loads
            __builtin_amdgcn_fence(__ATOMIC_ACQUIRE, "agent");
        }

        // ---- GEMM ----
        const bool gemm_active = cell ? (p >= 1) : true;
        if (gemm_active) {
            #pragma unroll
            for (int mt = 0; mt < 4; ++mt) {
                const int bm = mt * 16 + n15;
                const _Float16* a;
                if (cell == 0) {
                    if (kq < 4) a = xh + ((size_t)bm * TSTEPS + p) * DIM + kq * 256 + q * 8;
                    else        a = h0r + ((p - 1) & 3) * 65536 + bm * 1024 + (kq - 4) * 256 + q * 8;
                } else {
                    if (kq < 4) a = h0r + ((p - 1) & 3) * 65536 + bm * 1024 + kq * 256 + q * 8;
                    else        a = h1r + ((p - 2) & 3) * 65536 + bm * 1024 + (kq - 4) * 256 + q * 8;
                }
                f32x4 acc0 = {0.f, 0.f, 0.f, 0.f};
                f32x4 acc1 = {0.f, 0.f, 0.f, 0.f};
                #pragma unroll
                for (int kt = 0; kt < 8; ++kt) {
                    half8v av = *(const half8v*)(a + kt * 32);
                    acc0 = __builtin_amdgcn_mfma_f32_16x16x32_f16(av, wreg[kt],     acc0, 0, 0, 0);
                    acc1 = __builtin_amdgcn_mfma_f32_16x16x32_f16(av, wreg[8 + kt], acc1, 0, 0, 0);
                }
                const int row0 = mt * 16 + q * 4;
                #pragma unroll
                for (int r = 0; r < 4; ++r) {
                    gates[(kq * 64 + row0 + r) * GST + n15]      = acc0[r];
                    gates[(kq * 64 + row0 + r) * GST + 16 + n15] = acc1[r];
                }
            }
        }
        __syncthreads();

        // ---- pointwise ----
        if (gemm_active) {
            float g0 = 0.f, g1 = 0.f, g2 = 0.f, g3 = 0.f;
            #pragma unroll
            for (int k8 = 0; k8 < 8; ++k8) {
                const float* gsr = gates + (k8 * 64 + pb) * GST + pd;
                g0 += gsr[0]; g1 += gsr[8]; g2 += gsr[16]; g3 += gsr[24];
            }
            g0 += bi; g1 += bfg; g2 += bg; g3 += bo;
            float si = 1.f / (1.f + __expf(-g0));
            float sf = 1.f / (1.f + __expf(-g1));
            float so = 1.f / (1.f + __expf(-g3));
            float cn = sf * creg + si * tanhf(g2);
            float hn = so * tanhf(cn);
            creg = cn;
            union { _Float16 h; unsigned short u; } cv; cv.h = (_Float16)hn;
            _Float16* dst = cell ? (h1r + ((p - 1) & 3) * 65536)
                                 : (h0r + (p & 3) * 65536);
            __hip_atomic_store((unsigned short*)(dst + pb * 1024 + gdim),
                               cv.u, __ATOMIC_RELAXED, __HIP_MEMORY_SCOPE_AGENT);
            if (cell && p == TSTEPS) out[pb * 1024 + gdim] = hn;
        }

        // ---- signal phase completion ----
        if (p < TSTEPS) {
            asm volatile("s_waitcnt vmcnt(0)" ::: "memory");   // h stores at L3
            __syncthreads();
            if (tid == 0)
                __hip_atomic_fetch_add((cell ? cnt1 : cnt0) + p, 1u,
                                       __ATOMIC_RELAXED, __HIP_MEMORY_SCOPE_AGENT);
        }
    }
}

extern "C" void kernel_launch(void* const* d_in, const int* in_sizes, int n_in,
                              void* d_out, int out_size, void* d_ws, size_t ws_size,
                              hipStream_t stream)
{
    const float* x   = (const float*)d_in[0];
    const float* Wx0 = (const float*)d_in[1];
    const float* Wh0 = (const float*)d_in[2];
    const float* b0  = (const float*)d_in[3];
    const float* Wx1 = (const float*)d_in[4];
    const float* Wh1 = (const float*)d_in[5];
    const float* b1  = (const float*)d_in[6];
    float* out = (float*)d_out;

    _Float16* xh   = (_Float16*)d_ws;
    _Float16* h0r  = xh + (size_t)16777216;
    _Float16* h1r  = h0r + 262144;
    unsigned* cnt0 = (unsigned*)(h1r + 262144);
    unsigned* cnt1 = cnt0 + 256;

    hipLaunchKernelGGL(prologue, dim3(2048), dim3(256), 0, stream, x, xh, h0r, cnt0);

    size_t smem = 131072;
    (void)hipFuncSetAttribute((const void*)lstm_persistent,
                              hipFuncAttributeMaxDynamicSharedMemorySize, (int)smem);

    void* args[] = {(void*)&Wx0, (void*)&Wh0, (void*)&b0,
                    (void*)&Wx1, (void*)&Wh1, (void*)&b1,
                    (void*)&xh, (void*)&h0r, (void*)&h1r,
                    (void*)&cnt0, (void*)&cnt1, (void*)&out};
    (void)hipLaunchCooperativeKernel((const void*)lstm_persistent, dim3(256), dim3(512),
                                     args, (unsigned)smem, stream);
}

// Round 7
// 6859.663 us; speedup vs baseline: 1.1263x; 1.1263x over previous
//
#include <hip/hip_runtime.h>
#include <cmath>

#define TSTEPS 256
#define DIM 1024
#define GST 35            // gate scratch col-stride (32+3)

typedef _Float16 half8v __attribute__((ext_vector_type(8)));
typedef _Float16 half4v __attribute__((ext_vector_type(4)));
typedef float f32x4 __attribute__((ext_vector_type(4)));

// ws layout (halfs):
//   xh  : [T][B][D] fp16 x (t-major!), 16,777,216 halfs
//   h0r : [4 slot][64][1024] ring for h0
//   h1r : [4 slot][64][1024] ring for h1
//   cnt0/cnt1 : per-phase completion counters (256 each)
// Phase p: cell0 computes h0[t=p] (reads x[p], h0[p-1]); cell1 computes
// h1[t=p-1] (reads h0[p-1], h1[p-2]). h[t] in ring slot t&3.

__global__ void prologue(const float* __restrict__ x, _Float16* __restrict__ xh,
                         _Float16* __restrict__ hrings, unsigned* __restrict__ cnts)
{
    size_t gid  = (size_t)blockIdx.x * blockDim.x + threadIdx.x;
    size_t nthr = (size_t)gridDim.x * blockDim.x;
    for (size_t i = gid; i < 4194304u; i += nthr) {     // x[b][t][d4] -> xh[t][b][d]
        float4 v = ((const float4*)x)[i];
        half4v h = {(_Float16)v.x, (_Float16)v.y, (_Float16)v.z, (_Float16)v.w};
        unsigned d4 = (unsigned)i & 255u, t = ((unsigned)i >> 8) & 255u, b = (unsigned)i >> 16;
        ((half4v*)(xh + ((size_t)t * 64 + b) * 1024))[d4] = h;
    }
    for (size_t i = gid; i < 65536u; i += nthr) {       // zero both h rings
        half8v z = {};
        ((half8v*)hrings)[i] = z;
    }
    if (gid < 512) cnts[gid] = 0u;
}

__device__ __forceinline__ void poll_ge(const unsigned* c, unsigned tgt) {
    while (__hip_atomic_load(c, __ATOMIC_RELAXED, __HIP_MEMORY_SCOPE_AGENT) < tgt)
        __builtin_amdgcn_s_sleep(1);
}

// 256 blocks x 512 threads (8 waves, 2/SIMD). Blocks 0..127: cell0; 128..255:
// cell1. Block owns 32 gate-cols = 8 h-dims. Wave kq owns K-slice
// [kq*256, kq*256+256), weights in registers (16 x half8v = 64 VGPR).
// A-loads are double-buffered 8-deep across the mt loop (VGPR ~160) so load
// latency pipelines instead of serializing (R6's VGPR=68 left 1 buffer ->
// ~25us/phase of exposed latency). h reads: plain cached loads, coherence via
// per-phase agent acquire fence after the poll. h writes: agent-scope
// write-through. Sync: per-phase counters, one poller/block, s_sleep backoff.
__global__ __launch_bounds__(512, 2)
void lstm_persistent(const float* __restrict__ Wx0, const float* __restrict__ Wh0,
                     const float* __restrict__ b0,
                     const float* __restrict__ Wx1, const float* __restrict__ Wh1,
                     const float* __restrict__ b1,
                     const _Float16* __restrict__ xh, _Float16* __restrict__ h0r,
                     _Float16* __restrict__ h1r, unsigned* __restrict__ cnt0,
                     unsigned* __restrict__ cnt1, float* __restrict__ out)
{
    extern __shared__ char smem[];
    _Float16* wfrag = (_Float16*)smem;          // 128 KB staging (dead after init)
    float*    gates = (float*)smem;             // [8 kq][64 m][GST] fp32, aliases

    const int tid  = threadIdx.x;
    const int blk  = blockIdx.x;
    const int cell = blk >> 7;
    const int wb   = blk & 127;
    const int lane = tid & 63, kq = tid >> 6;
    const int n15 = lane & 15, q = lane >> 4;

    // ---- one-time: weights -> LDS in B-fragment order (fp32->fp16) ----
    const float* m0 = cell ? Wx1 : Wx0;
    const float* m1 = cell ? Wh1 : Wh0;
    for (int idx = tid; idx < 16384; idx += 512) {
        int k = idx >> 3;
        int cc0 = (idx & 7) * 4;
        int g = cc0 >> 3, c = cc0 & 7;
        const float* src = (k < 1024 ? m0 + (size_t)k * 4096
                                     : m1 + (size_t)(k - 1024) * 4096)
                           + g * 1024 + wb * 8 + c;
        float4 v = *(const float4*)src;
        int skq = k >> 8, kt = (k >> 5) & 7, sq = (k >> 3) & 3, j = k & 7;
        float vv[4] = {v.x, v.y, v.z, v.w};
        #pragma unroll
        for (int e = 0; e < 4; ++e) {
            int cc = cc0 + e, nt = cc >> 4, nn = cc & 15;
            wfrag[((((skq * 2 + nt) * 8 + kt) * 64) + sq * 16 + nn) * 8 + j] = (_Float16)vv[e];
        }
    }
    __syncthreads();

    half8v wreg[16];                      // [nt*8 + kt]
    #pragma unroll
    for (int nt = 0; nt < 2; ++nt)
        #pragma unroll
        for (int kt = 0; kt < 8; ++kt)
            wreg[nt * 8 + kt] = *(const half8v*)
                &wfrag[((((kq * 2 + nt) * 8 + kt) * 64) + lane) * 8];
    __syncthreads();                      // wfrag dead; gates alias it

    const int pb = tid >> 3, pd = tid & 7;
    const float* bias = cell ? b1 : b0;
    const int gdim = wb * 8 + pd;
    const float bi = bias[0 * 1024 + gdim], bfg = bias[1 * 1024 + gdim],
                bg = bias[2 * 1024 + gdim], bo  = bias[3 * 1024 + gdim];
    float creg = 0.0f;

    const bool havex = (cell == 0) && (kq < 4);   // wave reads x (no fence needed)

    for (int p = 0; p <= TSTEPS; ++p) {
        if (cell == 0 && p == TSTEPS) break;
        const bool active = cell ? (p >= 1) : true;

        half8v cur[8];
        // x-prefetch BEFORE the poll: x needs no coherence; the poll barrier's
        // vmcnt drain completes these behind the dependency wait.
        if (havex) {
            const _Float16* a = xh + (size_t)p * 65536 + (size_t)n15 * 1024
                                + kq * 256 + q * 8;
            #pragma unroll
            for (int kt = 0; kt < 8; ++kt) cur[kt] = *(const half8v*)(a + kt * 32);
        }

        // ---- wait for dependencies (one poller, sleep backoff) ----
        if (p >= 1) {
            if (tid == 0) {
                poll_ge(cnt0 + (p - 1), 128u);                  // h0[p-1] ready
                if (cell == 0) {
                    if (p >= 3) poll_ge(cnt1 + (p - 3), 128u);  // WAR: h0 ring
                } else {
                    if (p >= 2) poll_ge(cnt1 + (p - 1), 128u);  // h1[p-2] ready
                }
            }
            __syncthreads();
            __builtin_amdgcn_fence(__ATOMIC_ACQUIRE, "agent"); // inv L1/L2
        }

        // ---- GEMM, A double-buffered 8-deep across mt ----
        if (active) {
            const _Float16* arow;
            if (cell == 0) {
                arow = (kq < 4) ? xh + (size_t)p * 65536 + kq * 256
                                : h0r + ((p - 1) & 3) * 65536 + (kq - 4) * 256;
            } else {
                arow = (kq < 4) ? h0r + ((p - 1) & 3) * 65536 + kq * 256
                                : h1r + ((p - 2) & 3) * 65536 + (kq - 4) * 256;
            }
            const _Float16* ap = arow + (size_t)n15 * 1024 + q * 8;
            if (!havex) {
                #pragma unroll
                for (int kt = 0; kt < 8; ++kt) cur[kt] = *(const half8v*)(ap + kt * 32);
            }
            #pragma unroll
            for (int mt = 0; mt < 4; ++mt) {
                half8v nxt[8];
                if (mt < 3) {
                    const _Float16* ap2 = ap + (mt + 1) * 16384;
                    #pragma unroll
                    for (int kt = 0; kt < 8; ++kt) nxt[kt] = *(const half8v*)(ap2 + kt * 32);
                }
                f32x4 acc0 = {0.f, 0.f, 0.f, 0.f};
                f32x4 acc1 = {0.f, 0.f, 0.f, 0.f};
                #pragma unroll
                for (int kt = 0; kt < 8; ++kt) {
                    acc0 = __builtin_amdgcn_mfma_f32_16x16x32_f16(cur[kt], wreg[kt],     acc0, 0, 0, 0);
                    acc1 = __builtin_amdgcn_mfma_f32_16x16x32_f16(cur[kt], wreg[8 + kt], acc1, 0, 0, 0);
                }
                const int row0 = mt * 16 + q * 4;
                #pragma unroll
                for (int r = 0; r < 4; ++r) {
                    gates[(kq * 64 + row0 + r) * GST + n15]      = acc0[r];
                    gates[(kq * 64 + row0 + r) * GST + 16 + n15] = acc1[r];
                }
                if (mt < 3) {
                    #pragma unroll
                    for (int kt = 0; kt < 8; ++kt) cur[kt] = nxt[kt];
                }
            }
        }
        __syncthreads();

        // ---- pointwise ----
        if (active) {
            float g0 = 0.f, g1 = 0.f, g2 = 0.f, g3 = 0.f;
            #pragma unroll
            for (int k8 = 0; k8 < 8; ++k8) {
                const float* gsr = gates + (k8 * 64 + pb) * GST + pd;
                g0 += gsr[0]; g1 += gsr[8]; g2 += gsr[16]; g3 += gsr[24];
            }
            g0 += bi; g1 += bfg; g2 += bg; g3 += bo;
            float si = 1.f / (1.f + __expf(-g0));
            float sf = 1.f / (1.f + __expf(-g1));
            float so = 1.f / (1.f + __expf(-g3));
            float cn = sf * creg + si * tanhf(g2);
            float hn = so * tanhf(cn);
            creg = cn;
            union { _Float16 h; unsigned short u; } cv; cv.h = (_Float16)hn;
            _Float16* dst = cell ? (h1r + ((p - 1) & 3) * 65536)
                                 : (h0r + (p & 3) * 65536);
            __hip_atomic_store((unsigned short*)(dst + pb * 1024 + gdim),
                               cv.u, __ATOMIC_RELAXED, __HIP_MEMORY_SCOPE_AGENT);
            if (cell && p == TSTEPS) out[pb * 1024 + gdim] = hn;
        }

        // ---- signal phase completion ----
        if (p < TSTEPS) {
            asm volatile("s_waitcnt vmcnt(0)" ::: "memory");   // h stores at L3
            __syncthreads();
            if (tid == 0)
                __hip_atomic_fetch_add((cell ? cnt1 : cnt0) + p, 1u,
                                       __ATOMIC_RELAXED, __HIP_MEMORY_SCOPE_AGENT);
        }
    }
}

extern "C" void kernel_launch(void* const* d_in, const int* in_sizes, int n_in,
                              void* d_out, int out_size, void* d_ws, size_t ws_size,
                              hipStream_t stream)
{
    const float* x   = (const float*)d_in[0];
    const float* Wx0 = (const float*)d_in[1];
    const float* Wh0 = (const float*)d_in[2];
    const float* b0  = (const float*)d_in[3];
    const float* Wx1 = (const float*)d_in[4];
    const float* Wh1 = (const float*)d_in[5];
    const float* b1  = (const float*)d_in[6];
    float* out = (float*)d_out;

    _Float16* xh   = (_Float16*)d_ws;
    _Float16* h0r  = xh + (size_t)16777216;
    _Float16* h1r  = h0r + 262144;
    unsigned* cnt0 = (unsigned*)(h1r + 262144);
    unsigned* cnt1 = cnt0 + 256;

    hipLaunchKernelGGL(prologue, dim3(2048), dim3(256), 0, stream, x, xh, h0r, cnt0);

    size_t smem = 131072;
    (void)hipFuncSetAttribute((const void*)lstm_persistent,
                              hipFuncAttributeMaxDynamicSharedMemorySize, (int)smem);

    void* args[] = {(void*)&Wx0, (void*)&Wh0, (void*)&b0,
                    (void*)&Wx1, (void*)&Wh1, (void*)&b1,
                    (void*)&xh, (void*)&h0r, (void*)&h1r,
                    (void*)&cnt0, (void*)&cnt1, (void*)&out};
    (void)hipLaunchCooperativeKernel((const void*)lstm_persistent, dim3(256), dim3(512),
                                     args, (unsigned)smem, stream);
}

// Round 8
// 4881.528 us; speedup vs baseline: 1.5827x; 1.4052x over previous
//
#include <hip/hip_runtime.h>
#include <cmath>

#define TSTEPS 256
#define DIM 1024
#define GST 35            // gate scratch col-stride

typedef _Float16 half8v __attribute__((ext_vector_type(8)));
typedef _Float16 half4v __attribute__((ext_vector_type(4)));
typedef float f32x4 __attribute__((ext_vector_type(4)));
typedef unsigned long long u64;

// ws layout:
//   xh  : [T][B][D] fp16 x (t-major), 16,777,216 halfs
//   h0r : [4 slot][64][1024] ring for h0
//   h1r : [4 slot][64][1024] ring for h1
//   cnts: leaf0[256*16 stride16] leaf1[...] root0[256 stride16] root1[...]
//         (139,264 uints total)
// Phase p: cell0 computes h0[t=p] (reads x[p], h0[p-1]); cell1 computes
// h1[t=p-1] (reads h0[p-1], h1[p-2]). h[t] in ring slot t&3.

__global__ void prologue(const float* __restrict__ x, _Float16* __restrict__ xh,
                         _Float16* __restrict__ hrings, unsigned* __restrict__ cnts)
{
    size_t gid  = (size_t)blockIdx.x * blockDim.x + threadIdx.x;
    size_t nthr = (size_t)gridDim.x * blockDim.x;
    for (size_t i = gid; i < 4194304u; i += nthr) {     // x[b][t][d4] -> xh[t][b][d]
        float4 v = ((const float4*)x)[i];
        half4v h = {(_Float16)v.x, (_Float16)v.y, (_Float16)v.z, (_Float16)v.w};
        unsigned d4 = (unsigned)i & 255u, t = ((unsigned)i >> 8) & 255u, b = (unsigned)i >> 16;
        ((half4v*)(xh + ((size_t)t * 64 + b) * 1024))[d4] = h;
    }
    for (size_t i = gid; i < 65536u; i += nthr) {       // zero both h rings
        half8v z = {};
        ((half8v*)hrings)[i] = z;
    }
    for (size_t i = gid; i < 139264u; i += nthr) cnts[i] = 0u;
}

__device__ __forceinline__ void poll_eq16(const unsigned* c) {
    while (__hip_atomic_load(c, __ATOMIC_RELAXED, __HIP_MEMORY_SCOPE_AGENT) < 16u)
        __builtin_amdgcn_s_sleep(1);
}

__device__ __forceinline__ half8v load_h8_agent(const _Float16* p) {
    union { u64 u[2]; half8v v; } t;
    t.u[0] = __hip_atomic_load((const u64*)p,     __ATOMIC_RELAXED, __HIP_MEMORY_SCOPE_AGENT);
    t.u[1] = __hip_atomic_load((const u64*)p + 1, __ATOMIC_RELAXED, __HIP_MEMORY_SCOPE_AGENT);
    return t.v;
}

// 256 blocks x 512 threads (8 waves). Blocks 0..127: cell0; 128..255: cell1.
// Block owns 32 gate-cols = 8 h-dims. Wave kq owns K-slice [kq*256,+256),
// weights in registers (16 x half8v = 64 VGPR). A held as A[4][8] = 128 VGPR,
// loaded in ONE 32-load burst (single latency exposure). h reads: agent-scope
// (L3-direct, no fence, no L2 inv — x stays L2-warm). h writes: agent-scope
// write-through. Signal: leaf(16x8)->root tree, one poller/block, s_sleep.
__global__ __launch_bounds__(512, 2)
void lstm_persistent(const float* __restrict__ Wx0, const float* __restrict__ Wh0,
                     const float* __restrict__ b0,
                     const float* __restrict__ Wx1, const float* __restrict__ Wh1,
                     const float* __restrict__ b1,
                     const _Float16* __restrict__ xh, _Float16* __restrict__ h0r,
                     _Float16* __restrict__ h1r, unsigned* __restrict__ cnts,
                     float* __restrict__ out)
{
    extern __shared__ char smem[];
    _Float16* wfrag = (_Float16*)smem;          // 128 KB staging (dead after init)
    float*    gates = (float*)smem;             // [8 kq][64 m][GST] fp32, aliases

    const int tid  = threadIdx.x;
    const int blk  = blockIdx.x;
    const int cell = blk >> 7;
    const int wb   = blk & 127;
    const int lane = tid & 63, kq = tid >> 6;
    const int n15 = lane & 15, q = lane >> 4;

    unsigned* leafc = cnts + (cell ? 65536 : 0);        // [p*16+leaf] stride 16
    unsigned* root0 = cnts + 131072;                    // [p] stride 16
    unsigned* root1 = cnts + 135168;
    unsigned* rooto = cell ? root1 : root0;
    const int leaf  = wb >> 3;

    // ---- one-time: weights -> LDS in B-fragment order (fp32->fp16) ----
    const float* m0 = cell ? Wx1 : Wx0;
    const float* m1 = cell ? Wh1 : Wh0;
    for (int idx = tid; idx < 16384; idx += 512) {
        int k = idx >> 3;
        int cc0 = (idx & 7) * 4;
        int g = cc0 >> 3, c = cc0 & 7;
        const float* src = (k < 1024 ? m0 + (size_t)k * 4096
                                     : m1 + (size_t)(k - 1024) * 4096)
                           + g * 1024 + wb * 8 + c;
        float4 v = *(const float4*)src;
        int skq = k >> 8, kt = (k >> 5) & 7, sq = (k >> 3) & 3, j = k & 7;
        float vv[4] = {v.x, v.y, v.z, v.w};
        #pragma unroll
        for (int e = 0; e < 4; ++e) {
            int cc = cc0 + e, nt = cc >> 4, nn = cc & 15;
            wfrag[((((skq * 2 + nt) * 8 + kt) * 64) + sq * 16 + nn) * 8 + j] = (_Float16)vv[e];
        }
    }
    __syncthreads();

    half8v wreg[16];                      // [nt*8 + kt]
    #pragma unroll
    for (int nt = 0; nt < 2; ++nt)
        #pragma unroll
        for (int kt = 0; kt < 8; ++kt)
            wreg[nt * 8 + kt] = *(const half8v*)
                &wfrag[((((kq * 2 + nt) * 8 + kt) * 64) + lane) * 8];
    __syncthreads();                      // wfrag dead; gates alias it

    const int pb = tid >> 3, pd = tid & 7;
    const float* bias = cell ? b1 : b0;
    const int gdim = wb * 8 + pd;
    const float bi = bias[0 * 1024 + gdim], bfg = bias[1 * 1024 + gdim],
                bg = bias[2 * 1024 + gdim], bo  = bias[3 * 1024 + gdim];
    float creg = 0.0f;

    const bool havex = (cell == 0) && (kq < 4);   // x-wave: plain cached loads

    for (int p = 0; p <= TSTEPS; ++p) {
        if (cell == 0 && p == TSTEPS) break;
        const bool active = cell ? (p >= 1) : true;

        half8v A[4][8];
        // x burst BEFORE the poll (no coherence needed; overlaps the wait)
        if (havex) {
            const _Float16* a = xh + (size_t)p * 65536 + (size_t)n15 * 1024
                                + kq * 256 + q * 8;
            #pragma unroll
            for (int mt = 0; mt < 4; ++mt)
                #pragma unroll
                for (int kt = 0; kt < 8; ++kt)
                    A[mt][kt] = *(const half8v*)(a + mt * 16384 + kt * 32);
        }

        // ---- wait for dependencies (one poller, sleep backoff) ----
        if (p >= 1) {
            if (tid == 0) {
                poll_eq16(root0 + (p - 1) * 16);                 // h0[p-1] ready
                if (cell == 0) {
                    if (p >= 3) poll_eq16(root1 + (p - 3) * 16); // WAR: h0 ring
                } else {
                    if (p >= 2) poll_eq16(root1 + (p - 1) * 16); // h1[p-2] ready
                }
            }
            __syncthreads();
        }

        // ---- h burst: 32 agent-scope loads, one latency exposure ----
        if (active && !havex) {
            const _Float16* arow;
            if (cell == 0) {
                arow = h0r + ((p - 1) & 3) * 65536 + (kq - 4) * 256;
            } else {
                arow = (kq < 4) ? h0r + ((p - 1) & 3) * 65536 + kq * 256
                                : h1r + ((p - 2) & 3) * 65536 + (kq - 4) * 256;
            }
            const _Float16* a = arow + (size_t)n15 * 1024 + q * 8;
            #pragma unroll
            for (int mt = 0; mt < 4; ++mt)
                #pragma unroll
                for (int kt = 0; kt < 8; ++kt)
                    A[mt][kt] = load_h8_agent(a + mt * 16384 + kt * 32);
        }

        // ---- MFMA ----
        if (active) {
            #pragma unroll
            for (int mt = 0; mt < 4; ++mt) {
                f32x4 acc0 = {0.f, 0.f, 0.f, 0.f};
                f32x4 acc1 = {0.f, 0.f, 0.f, 0.f};
                #pragma unroll
                for (int kt = 0; kt < 8; ++kt) {
                    acc0 = __builtin_amdgcn_mfma_f32_16x16x32_f16(A[mt][kt], wreg[kt],     acc0, 0, 0, 0);
                    acc1 = __builtin_amdgcn_mfma_f32_16x16x32_f16(A[mt][kt], wreg[8 + kt], acc1, 0, 0, 0);
                }
                const int row0 = mt * 16 + q * 4;
                #pragma unroll
                for (int r = 0; r < 4; ++r) {
                    gates[(kq * 64 + row0 + r) * GST + n15]      = acc0[r];
                    gates[(kq * 64 + row0 + r) * GST + 16 + n15] = acc1[r];
                }
            }
        }
        __syncthreads();

        // ---- pointwise ----
        if (active) {
            float g0 = 0.f, g1 = 0.f, g2 = 0.f, g3 = 0.f;
            #pragma unroll
            for (int k8 = 0; k8 < 8; ++k8) {
                const float* gsr = gates + (k8 * 64 + pb) * GST + pd;
                g0 += gsr[0]; g1 += gsr[8]; g2 += gsr[16]; g3 += gsr[24];
            }
            g0 += bi; g1 += bfg; g2 += bg; g3 += bo;
            float si = 1.f / (1.f + __expf(-g0));
            float sf = 1.f / (1.f + __expf(-g1));
            float so = 1.f / (1.f + __expf(-g3));
            float cn = sf * creg + si * tanhf(g2);
            float hn = so * tanhf(cn);
            creg = cn;
            union { _Float16 h; unsigned short u; } cv; cv.h = (_Float16)hn;
            _Float16* dst = cell ? (h1r + ((p - 1) & 3) * 65536)
                                 : (h0r + (p & 3) * 65536);
            __hip_atomic_store((unsigned short*)(dst + pb * 1024 + gdim),
                               cv.u, __ATOMIC_RELAXED, __HIP_MEMORY_SCOPE_AGENT);
            if (cell && p == TSTEPS) out[pb * 1024 + gdim] = hn;
        }

        // ---- signal: leaf -> root tree ----
        if (p < TSTEPS) {
            asm volatile("s_waitcnt vmcnt(0)" ::: "memory");   // h stores at L3
            __syncthreads();
            if (tid == 0) {
                unsigned old = __hip_atomic_fetch_add(leafc + (p * 16 + leaf) * 16, 1u,
                                                      __ATOMIC_RELAXED, __HIP_MEMORY_SCOPE_AGENT);
                if (old == 7u)
                    __hip_atomic_fetch_add(rooto + p * 16, 1u,
                                           __ATOMIC_RELAXED, __HIP_MEMORY_SCOPE_AGENT);
            }
        }
    }
}

extern "C" void kernel_launch(void* const* d_in, const int* in_sizes, int n_in,
                              void* d_out, int out_size, void* d_ws, size_t ws_size,
                              hipStream_t stream)
{
    const float* x   = (const float*)d_in[0];
    const float* Wx0 = (const float*)d_in[1];
    const float* Wh0 = (const float*)d_in[2];
    const float* b0  = (const float*)d_in[3];
    const float* Wx1 = (const float*)d_in[4];
    const float* Wh1 = (const float*)d_in[5];
    const float* b1  = (const float*)d_in[6];
    float* out = (float*)d_out;

    _Float16* xh   = (_Float16*)d_ws;
    _Float16* h0r  = xh + (size_t)16777216;
    _Float16* h1r  = h0r + 262144;
    unsigned* cnts = (unsigned*)(h1r + 262144);

    hipLaunchKernelGGL(prologue, dim3(2048), dim3(256), 0, stream, x, xh, h0r, cnts);

    size_t smem = 131072;
    (void)hipFuncSetAttribute((const void*)lstm_persistent,
                              hipFuncAttributeMaxDynamicSharedMemorySize, (int)smem);

    void* args[] = {(void*)&Wx0, (void*)&Wh0, (void*)&b0,
                    (void*)&Wx1, (void*)&Wh1, (void*)&b1,
                    (void*)&xh, (void*)&h0r, (void*)&h1r,
                    (void*)&cnts, (void*)&out};
    (void)hipLaunchCooperativeKernel((const void*)lstm_persistent, dim3(256), dim3(512),
                                     args, (unsigned)smem, stream);
}

// Round 9
// 4812.533 us; speedup vs baseline: 1.6054x; 1.0143x over previous
//
#include <hip/hip_runtime.h>
#include <cmath>

#define TSTEPS 256
#define DIM 1024
#define GST 35            // gate scratch col-stride

typedef _Float16 half8v __attribute__((ext_vector_type(8)));
typedef _Float16 half4v __attribute__((ext_vector_type(4)));
typedef float f32x4 __attribute__((ext_vector_type(4)));
typedef unsigned long long u64;

// ws layout:
//   xh  : [T][B][D] fp16 x (t-major), 16,777,216 halfs
//   h0r : [4 slot][64][1024] ring for h0
//   h1r : [4 slot][64][1024] ring for h1
//   cnts: leaf0[p][16 leaves, 16-word stride], leaf1[...] (131,072 uints)
// Phase p: cell0 computes h0[t=p] (reads x[p], h0[p-1]); cell1 computes
// h1[t=p-1] (reads h0[p-1], h1[p-2]). h[t] in ring slot t&3.

__global__ void prologue(const float* __restrict__ x, _Float16* __restrict__ xh,
                         _Float16* __restrict__ hrings, unsigned* __restrict__ cnts)
{
    size_t gid  = (size_t)blockIdx.x * blockDim.x + threadIdx.x;
    size_t nthr = (size_t)gridDim.x * blockDim.x;
    for (size_t i = gid; i < 4194304u; i += nthr) {     // x[b][t][d4] -> xh[t][b][d]
        float4 v = ((const float4*)x)[i];
        half4v h = {(_Float16)v.x, (_Float16)v.y, (_Float16)v.z, (_Float16)v.w};
        unsigned d4 = (unsigned)i & 255u, t = ((unsigned)i >> 8) & 255u, b = (unsigned)i >> 16;
        ((half4v*)(xh + ((size_t)t * 64 + b) * 1024))[d4] = h;
    }
    for (size_t i = gid; i < 65536u; i += nthr) {       // zero both h rings
        half8v z = {};
        ((half8v*)hrings)[i] = z;
    }
    for (size_t i = gid; i < 139264u; i += nthr) cnts[i] = 0u;
}

__device__ __forceinline__ half8v load_h8_agent(const _Float16* p) {
    union { u64 u[2]; half8v v; } t;
    t.u[0] = __hip_atomic_load((const u64*)p,     __ATOMIC_RELAXED, __HIP_MEMORY_SCOPE_AGENT);
    t.u[1] = __hip_atomic_load((const u64*)p + 1, __ATOMIC_RELAXED, __HIP_MEMORY_SCOPE_AGENT);
    return t.v;
}

// 256 blocks x 512 threads (8 waves). Blocks 0..127: cell0; 128..255: cell1.
// Block owns 32 gate-cols = 8 h-dims. Wave kq owns K-slice [kq*256,+256),
// weights in registers (16 x half8v). A held as A[4][8], loaded in one
// 32-load burst. h reads/writes: agent-scope (L3, no fences). Signal: 16 leaf
// counters/cell/phase (8 adds each, 64B apart). Wait: wave 0 lanes 0..31 poll
// all leaves of BOTH dep sets in parallel + ballot, s_sleep(16) pacing, latch
// satisfied lanes -> poll traffic far below L3 line service rate (R8 lesson:
// 256 pollers + s_sleep(1) on ONE root line oversubscribed it 4-8x).
__global__ __launch_bounds__(512, 2)
void lstm_persistent(const float* __restrict__ Wx0, const float* __restrict__ Wh0,
                     const float* __restrict__ b0,
                     const float* __restrict__ Wx1, const float* __restrict__ Wh1,
                     const float* __restrict__ b1,
                     const _Float16* __restrict__ xh, _Float16* __restrict__ h0r,
                     _Float16* __restrict__ h1r, unsigned* __restrict__ cnts,
                     float* __restrict__ out)
{
    extern __shared__ char smem[];
    _Float16* wfrag = (_Float16*)smem;          // 128 KB staging (dead after init)
    float*    gates = (float*)smem;             // [8 kq][64 m][GST] fp32, aliases

    const int tid  = threadIdx.x;
    const int blk  = blockIdx.x;
    const int cell = blk >> 7;
    const int wb   = blk & 127;
    const int lane = tid & 63, kq = tid >> 6;
    const int n15 = lane & 15, q = lane >> 4;

    unsigned* leaf0 = cnts;                     // [(p*16+leaf)*16]
    unsigned* leaf1 = cnts + 65536;
    unsigned* leafm = cell ? leaf1 : leaf0;

    // ---- one-time: weights -> LDS in B-fragment order (fp32->fp16) ----
    const float* m0 = cell ? Wx1 : Wx0;
    const float* m1 = cell ? Wh1 : Wh0;
    for (int idx = tid; idx < 16384; idx += 512) {
        int k = idx >> 3;
        int cc0 = (idx & 7) * 4;
        int g = cc0 >> 3, c = cc0 & 7;
        const float* src = (k < 1024 ? m0 + (size_t)k * 4096
                                     : m1 + (size_t)(k - 1024) * 4096)
                           + g * 1024 + wb * 8 + c;
        float4 v = *(const float4*)src;
        int skq = k >> 8, kt = (k >> 5) & 7, sq = (k >> 3) & 3, j = k & 7;
        float vv[4] = {v.x, v.y, v.z, v.w};
        #pragma unroll
        for (int e = 0; e < 4; ++e) {
            int cc = cc0 + e, nt = cc >> 4, nn = cc & 15;
            wfrag[((((skq * 2 + nt) * 8 + kt) * 64) + sq * 16 + nn) * 8 + j] = (_Float16)vv[e];
        }
    }
    __syncthreads();

    half8v wreg[16];                      // [nt*8 + kt]
    #pragma unroll
    for (int nt = 0; nt < 2; ++nt)
        #pragma unroll
        for (int kt = 0; kt < 8; ++kt)
            wreg[nt * 8 + kt] = *(const half8v*)
                &wfrag[((((kq * 2 + nt) * 8 + kt) * 64) + lane) * 8];
    __syncthreads();                      // wfrag dead; gates alias it

    const int pb = tid >> 3, pd = tid & 7;
    const float* bias = cell ? b1 : b0;
    const int gdim = wb * 8 + pd;
    const float bi = bias[0 * 1024 + gdim], bfg = bias[1 * 1024 + gdim],
                bg = bias[2 * 1024 + gdim], bo  = bias[3 * 1024 + gdim];
    float creg = 0.0f;

    const bool havex = (cell == 0) && (kq < 4);   // x-wave: plain cached loads

    for (int p = 0; p <= TSTEPS; ++p) {
        if (cell == 0 && p == TSTEPS) break;
        const bool active = cell ? (p >= 1) : true;

        half8v A[4][8];
        // x burst BEFORE the poll (no coherence needed; overlaps the wait)
        if (havex) {
            const _Float16* a = xh + (size_t)p * 65536 + (size_t)n15 * 1024
                                + kq * 256 + q * 8;
            #pragma unroll
            for (int mt = 0; mt < 4; ++mt)
                #pragma unroll
                for (int kt = 0; kt < 8; ++kt)
                    A[mt][kt] = *(const half8v*)(a + mt * 16384 + kt * 32);
        }

        // ---- wait for dependencies: wave 0, leaf-parallel + ballot ----
        if (p >= 1) {
            if (tid < 64) {
                // set A: leaf0[p-1] (lanes 0..15). set B (lanes 16..31):
                //   cell0: leaf1[p-3] (ring WAR), cell1: leaf1[p-1]
                const unsigned* addr = nullptr;
                if (tid < 16) {
                    addr = leaf0 + ((p - 1) * 16 + tid) * 16;
                } else if (tid < 32) {
                    int lf = tid - 16;
                    if (cell == 0) { if (p >= 3) addr = leaf1 + ((p - 3) * 16 + lf) * 16; }
                    else           { if (p >= 2) addr = leaf1 + ((p - 1) * 16 + lf) * 16; }
                }
                bool ok = (addr == nullptr);
                while (true) {
                    if (!ok)
                        ok = __hip_atomic_load(addr, __ATOMIC_RELAXED,
                                               __HIP_MEMORY_SCOPE_AGENT) >= 8u;
                    if (__ballot(ok) == ~0ull) break;
                    __builtin_amdgcn_s_sleep(16);
                }
            }
            __syncthreads();
        }

        // ---- h burst: 32 agent-scope loads, one latency exposure ----
        if (active && !havex) {
            const _Float16* arow;
            if (cell == 0) {
                arow = h0r + ((p - 1) & 3) * 65536 + (kq - 4) * 256;
            } else {
                arow = (kq < 4) ? h0r + ((p - 1) & 3) * 65536 + kq * 256
                                : h1r + ((p - 2) & 3) * 65536 + (kq - 4) * 256;
            }
            const _Float16* a = arow + (size_t)n15 * 1024 + q * 8;
            #pragma unroll
            for (int mt = 0; mt < 4; ++mt)
                #pragma unroll
                for (int kt = 0; kt < 8; ++kt)
                    A[mt][kt] = load_h8_agent(a + mt * 16384 + kt * 32);
        }

        // ---- MFMA ----
        if (active) {
            #pragma unroll
            for (int mt = 0; mt < 4; ++mt) {
                f32x4 acc0 = {0.f, 0.f, 0.f, 0.f};
                f32x4 acc1 = {0.f, 0.f, 0.f, 0.f};
                #pragma unroll
                for (int kt = 0; kt < 8; ++kt) {
                    acc0 = __builtin_amdgcn_mfma_f32_16x16x32_f16(A[mt][kt], wreg[kt],     acc0, 0, 0, 0);
                    acc1 = __builtin_amdgcn_mfma_f32_16x16x32_f16(A[mt][kt], wreg[8 + kt], acc1, 0, 0, 0);
                }
                const int row0 = mt * 16 + q * 4;
                #pragma unroll
                for (int r = 0; r < 4; ++r) {
                    gates[(kq * 64 + row0 + r) * GST + n15]      = acc0[r];
                    gates[(kq * 64 + row0 + r) * GST + 16 + n15] = acc1[r];
                }
            }
        }
        __syncthreads();

        // ---- pointwise ----
        if (active) {
            float g0 = 0.f, g1 = 0.f, g2 = 0.f, g3 = 0.f;
            #pragma unroll
            for (int k8 = 0; k8 < 8; ++k8) {
                const float* gsr = gates + (k8 * 64 + pb) * GST + pd;
                g0 += gsr[0]; g1 += gsr[8]; g2 += gsr[16]; g3 += gsr[24];
            }
            g0 += bi; g1 += bfg; g2 += bg; g3 += bo;
            float si = 1.f / (1.f + __expf(-g0));
            float sf = 1.f / (1.f + __expf(-g1));
            float so = 1.f / (1.f + __expf(-g3));
            float cn = sf * creg + si * tanhf(g2);
            float hn = so * tanhf(cn);
            creg = cn;
            union { _Float16 h; unsigned short u; } cv; cv.h = (_Float16)hn;
            _Float16* dst = cell ? (h1r + ((p - 1) & 3) * 65536)
                                 : (h0r + (p & 3) * 65536);
            __hip_atomic_store((unsigned short*)(dst + pb * 1024 + gdim),
                               cv.u, __ATOMIC_RELAXED, __HIP_MEMORY_SCOPE_AGENT);
            if (cell && p == TSTEPS) out[pb * 1024 + gdim] = hn;
        }

        // ---- signal: one leaf add per block (8 blocks/leaf, 64B apart) ----
        if (p < TSTEPS) {
            asm volatile("s_waitcnt vmcnt(0)" ::: "memory");   // h stores at L3
            __syncthreads();
            if (tid == 0)
                __hip_atomic_fetch_add(leafm + (p * 16 + (wb >> 3)) * 16, 1u,
                                       __ATOMIC_RELAXED, __HIP_MEMORY_SCOPE_AGENT);
        }
    }
}

extern "C" void kernel_launch(void* const* d_in, const int* in_sizes, int n_in,
                              void* d_out, int out_size, void* d_ws, size_t ws_size,
                              hipStream_t stream)
{
    const float* x   = (const float*)d_in[0];
    const float* Wx0 = (const float*)d_in[1];
    const float* Wh0 = (const float*)d_in[2];
    const float* b0  = (const float*)d_in[3];
    const float* Wx1 = (const float*)d_in[4];
    const float* Wh1 = (const float*)d_in[5];
    const float* b1  = (const float*)d_in[6];
    float* out = (float*)d_out;

    _Float16* xh   = (_Float16*)d_ws;
    _Float16* h0r  = xh + (size_t)16777216;
    _Float16* h1r  = h0r + 262144;
    unsigned* cnts = (unsigned*)(h1r + 262144);

    hipLaunchKernelGGL(prologue, dim3(2048), dim3(256), 0, stream, x, xh, h0r, cnts);

    size_t smem = 131072;
    (void)hipFuncSetAttribute((const void*)lstm_persistent,
                              hipFuncAttributeMaxDynamicSharedMemorySize, (int)smem);

    void* args[] = {(void*)&Wx0, (void*)&Wh0, (void*)&b0,
                    (void*)&Wx1, (void*)&Wh1, (void*)&b1,
                    (void*)&xh, (void*)&h0r, (void*)&h1r,
                    (void*)&cnts, (void*)&out};
    (void)hipLaunchCooperativeKernel((const void*)lstm_persistent, dim3(256), dim3(512),
                                     args, (unsigned)smem, stream);
}